// Round 4
// baseline (653.995 us; speedup 1.0000x reference)
//
#include <hip/hip_runtime.h>

// out[b,c,n] = x[b,c, px*NY+py], px=trunc(clip(coords[b,n,1]*(NX-1),0,NX)),
//                                py=trunc(clip(coords[b,n,0]*(NY-1),0,NY))
//
// R7: R6's direct gather was LATENCY-bound, self-inflicted:
//   - launch_bounds(256,2) + grid=512 -> 8 waves/CU (Occupancy 22%)
//   - asm prefetch keep-alive serialized ~900cyc HBM waits into every iter
//   - ~8 outstanding 4B gathers/wave -> ~64/CU -> 0.2 loads/cyc -> 278us
// Fix: max MLP.
//   - grid 2048 (8 blocks/CU = 32 waves/CU, VGPR<64), no LDS, no prefetch
//   - every block sweeps ALL 128 channels in the same order: co-XCD blocks
//     (bid&7=b) stay lockstep; working set ~8 planes = 2MB < 4MB L2; the
//     gathers themselves populate L2 (MSHR-coalesced), x leaves HBM ~once
//   - 16 independent gathers in flight per wave (unroll 2 x 8 channels)
//     -> 512 outstanding/CU
//   - stores: coalesced 256B nontemporal along n (bypass L2, don't evict x)
// Traffic floor: x 268MB + out 134MB + coords 4MB ~= 406MB ~= 64us.
#define B_  8
#define C_  128
#define NX_ 256
#define NY_ 256
#define N_  32768
#define PLANE_ (NX_ * NY_)                       // 65536

__device__ __forceinline__ int sample_idx(const float* __restrict__ coords, int b, int n) {
    const float2 cc = *reinterpret_cast<const float2*>(coords + ((size_t)b * N_ + n) * 2);
    const int px = (int)fminf(fmaxf(cc.y * (float)(NX_ - 1), 0.0f), (float)NX_);
    const int py = (int)fminf(fmaxf(cc.x * (float)(NY_ - 1), 0.0f), (float)NY_);
    return min(px * NY_ + py, PLANE_ - 1);
}

// grid = B_ * (N_/128) = 2048 blocks; block = (b, 128-sample n-tile),
// thread t: sample s = t&127, channel half ch = (t>>7)*64.
__global__ __launch_bounds__(256) void gather_direct(const float* __restrict__ x,
                                                     const float* __restrict__ coords,
                                                     float* __restrict__ out) {
    const int bid = blockIdx.x;
    const int b   = bid & 7;                     // batch == XCD affinity
    const int nt  = bid >> 3;                    // 0..255
    const int n0  = nt << 7;                     // 128 samples per block
    const int t   = threadIdx.x;
    const int s   = t & 127;
    const int ch  = (t >> 7) << 6;               // 0 or 64

    const int idx = sample_idx(coords, b, n0 + s);

    const float* __restrict__ xb = x + ((size_t)b * C_ + ch) * PLANE_;
    float* __restrict__ ob = out + ((size_t)b * C_ + ch) * N_ + n0;

    #pragma unroll 2
    for (int c0 = 0; c0 < 64; c0 += 8) {
        float v[8];
        #pragma unroll
        for (int j = 0; j < 8; ++j)              // 8 independent gathers in flight
            v[j] = xb[(size_t)(c0 + j) * PLANE_ + idx];
        #pragma unroll
        for (int j = 0; j < 8; ++j)              // coalesced 256B NT stores along n
            __builtin_nontemporal_store(v[j], ob + (size_t)(c0 + j) * N_ + s);
    }
}

extern "C" void kernel_launch(void* const* d_in, const int* in_sizes, int n_in,
                              void* d_out, int out_size, void* d_ws, size_t ws_size,
                              hipStream_t stream) {
    const float* x      = (const float*)d_in[0];
    const float* coords = (const float*)d_in[1];
    float* out          = (float*)d_out;
    gather_direct<<<B_ * (N_ / 128), 256, 0, stream>>>(x, coords, out);
}